// Round 13
// baseline (1148.338 us; speedup 1.0000x reference)
//
#include <hip/hip_runtime.h>
#include <hip/hip_bf16.h>
#include <math.h>

#define S_LEN 512
#define B_SZ  256
#define E_DIM 128
#define HHID  128
#define G4    512   // 4*HH
#define T_TAG 9
#define NR    (S_LEN * B_SZ)   // r = s*256 + b
#define VOCAB 5001

typedef __attribute__((ext_vector_type(8))) short bf16x8;
typedef __attribute__((ext_vector_type(4))) float f32x4;

__device__ __forceinline__ float bf2f(__hip_bfloat16 v) { return __bfloat162float(v); }
__device__ __forceinline__ float scrub0(float v) {       // inf/nan -> 0
    unsigned u = __float_as_uint(v);
    return (((u >> 23) & 0xFFu) == 0xFFu) ? 0.f : v;
}
__device__ __forceinline__ float frcp(float x) { return __builtin_amdgcn_rcpf(x); }
__device__ __forceinline__ float fsig(float x) { return frcp(1.f + __expf(-x)); }
__device__ __forceinline__ float ftanh(float x) {
    return 1.f - 2.f * frcp(1.f + __expf(2.f * x));
}
// LDS-only barrier: waits ds ops (lgkmcnt) but NOT global stores/loads (vmcnt)
// — __syncthreads would drain vmcnt(0) every step (hs stores + E prefetch).
__device__ __forceinline__ void lds_barrier() {
    asm volatile("s_waitcnt lgkmcnt(0)\n\ts_barrier" ::: "memory");
}

// ---- .bss scratch (~150 MB) ----
__device__ __hip_bfloat16 g_emb[VOCAB * E_DIM];
__device__ __hip_bfloat16 g_wih[2][G4 * E_DIM];    // rows permuted: n' = 4u+g
__device__ __hip_bfloat16 g_whh2[2][G4 * HHID];    // rows permuted: n' = 4u+g
__device__ __align__(16) float g_bias[2][G4];      // permuted
__device__ float g_wout[T_TAG * 256];
__device__ float g_bout[T_TAG];
__device__ float g_trans[T_TAG * T_TAG];
__device__ float g_start[T_TAG];
__device__ float g_end[T_TAG];
__device__ float g_maskf[B_SZ * S_LEN];
__device__ float g_em[(long)NR * T_TAG];
__device__ __align__(16) float g_hs[2][(long)NR * HHID];  // [(s*16+bg)*128+u]*16+m

// -------------------------------------------------------------------------
// Canonicalize inputs (bf16/fp32 autodetect via mask). Gate permutation:
// row n' = 4u+g  <->  original torch gate row g*128+u.
// -------------------------------------------------------------------------
__global__ __launch_bounds__(256) void convert_kernel(
    const void* mask, const void* emb,
    const void* wih_f, const void* whh_f, const void* bih_f, const void* bhh_f,
    const void* wih_b, const void* whh_b, const void* bih_b, const void* bhh_b,
    const void* wout, const void* bout, const void* trans,
    const void* startt, const void* endt)
{
    const bool isb = (((const unsigned*)mask)[0] == 0x3F803F80u);
    auto ldf = [&](const void* p, long i) -> float {
        float v = isb ? bf2f(((const __hip_bfloat16*)p)[i]) : ((const float*)p)[i];
        return scrub0(v);
    };
    const long tid0   = (long)blockIdx.x * blockDim.x + threadIdx.x;
    const long stride = (long)gridDim.x * blockDim.x;

    for (long i = tid0; i < (long)VOCAB * E_DIM; i += stride)
        g_emb[i] = __float2bfloat16(ldf(emb, i));
    for (long i = tid0; i < (long)G4 * E_DIM; i += stride) {
        const int np = (int)(i >> 7), e = (int)(i & 127);
        const int g = np & 3, u = np >> 2;
        const long src = (long)(g * 128 + u) * E_DIM + e;
        g_wih[0][i] = __float2bfloat16(ldf(wih_f, src));
        g_wih[1][i] = __float2bfloat16(ldf(wih_b, src));
    }
    for (long i = tid0; i < (long)G4 * HHID; i += stride) {
        const int np = (int)(i >> 7), k = (int)(i & 127);
        const int g = np & 3, u = np >> 2;
        const long src = (long)(g * 128 + u) * HHID + k;
        g_whh2[0][i] = __float2bfloat16(ldf(whh_f, src));
        g_whh2[1][i] = __float2bfloat16(ldf(whh_b, src));
    }
    for (long i = tid0; i < G4; i += stride) {
        const int g = (int)i & 3, u = (int)i >> 2;
        const long src = g * 128 + u;
        g_bias[0][i] = ldf(bih_f, src) + ldf(bhh_f, src);
        g_bias[1][i] = ldf(bih_b, src) + ldf(bhh_b, src);
    }
    for (long i = tid0; i < T_TAG * 256; i += stride) g_wout[i] = ldf(wout, i);
    for (long i = tid0; i < T_TAG * T_TAG; i += stride) g_trans[i] = ldf(trans, i);
    for (long i = tid0; i < T_TAG; i += stride) {
        g_bout[i]  = ldf(bout, i);
        g_start[i] = ldf(startt, i);
        g_end[i]   = ldf(endt, i);
    }
    for (long i = tid0; i < (long)B_SZ * S_LEN; i += stride)
        g_maskf[i] = ldf(mask, i);
}

// -------------------------------------------------------------------------
// Fused MFMA scan: grid (16 bg, 2 dir), 512 thr. Per step:
//  - E prefetch for it+2 issued first (L2-resident, max distance)
//  - acc[t] = px[t] + Whh'@(h_hi+h_lo)^T  (C-chained, no copies)
//  - per tile: px[t] = bias + Wih'@E (MFMA) interleaved with act/c-update
//  - LDS-only barrier (no vmcnt drain)
// Lane (wv,quad,m16) tile t holds gates i,f,g,o (reg 0..3) of unit
// u=16wv+4t+quad, batch m16 -> c/h update fully in-lane.
// -------------------------------------------------------------------------
__global__ __launch_bounds__(512, 1) void scan_mfma(const int* __restrict__ x)
{
    __shared__ __align__(16) unsigned short hB[2][2][16 * 16 * 8];  // 16 KB
    __shared__ int xO[S_LEN * 16];   // premultiplied emb element offsets (32 KB)

    const int bg = blockIdx.x, dir = blockIdx.y;
    const int tid  = threadIdx.x;
    const int lane = tid & 63, wv = tid >> 6;
    const int m16  = lane & 15, quad = lane >> 4;

    // persistent A fragments: Whh' + Wih' rows (lane&15 = n_local)
    bf16x8 W[4][4], V[4][4];
    f32x4 bias4[4];
    #pragma unroll
    for (int t = 0; t < 4; t++) {
        const int np = (wv * 4 + t) * 16 + m16;
        #pragma unroll
        for (int kk = 0; kk < 4; kk++) {
            W[t][kk] = *(const bf16x8*)&g_whh2[dir][(long)np * HHID + kk * 32 + quad * 8];
            V[t][kk] = *(const bf16x8*)&g_wih[dir][(long)np * E_DIM + kk * 32 + quad * 8];
        }
        const int u = 16 * wv + 4 * t + quad;
        const float4 b4 = *(const float4*)&g_bias[dir][4 * u];
        bias4[t] = (f32x4){b4.x, b4.y, b4.z, b4.w};
    }
    {   // stage premultiplied token offsets: xO[s*16+m] = x[bg*16+m][s] * E_DIM
        const bool x64 = ((x[1] | x[3] | x[5] | x[7]) == 0);
        for (int i = tid; i < S_LEN * 16; i += 512) {
            const int s = i >> 4, m = i & 15;
            const int ii = (bg * 16 + m) * S_LEN + s;
            xO[i] = (x64 ? x[2 * ii] : x[ii]) * E_DIM;
        }
    }
    for (int i = tid; i < 2 * 2 * 2048; i += 512) ((unsigned short*)hB)[i] = 0;
    float c[4] = {0.f, 0.f, 0.f, 0.f};
    __syncthreads();   // full barrier once (xO + hB init visible)

    int se = dir ? (S_LEN - 1) : 0;
    const int step = dir ? -1 : 1;

    // prologue: px for step 0 from token se0; E <- fragments for step 1
    bf16x8 E[4];
    f32x4 px[4];
    {
        const int xo0 = xO[se * 16 + m16];
        #pragma unroll
        for (int kk = 0; kk < 4; kk++)
            E[kk] = *(const bf16x8*)&g_emb[(long)xo0 + kk * 32 + quad * 8];
        #pragma unroll
        for (int t = 0; t < 4; t++) {
            px[t] = __builtin_amdgcn_mfma_f32_16x16x32_bf16(V[t][0], E[0], bias4[t], 0, 0, 0);
            #pragma unroll
            for (int kk = 1; kk < 4; kk++)
                px[t] = __builtin_amdgcn_mfma_f32_16x16x32_bf16(V[t][kk], E[kk], px[t], 0, 0, 0);
        }
        const int xo1 = xO[(se + step) * 16 + m16];
        #pragma unroll
        for (int kk = 0; kk < 4; kk++)
            E[kk] = *(const bf16x8*)&g_emb[(long)xo1 + kk * 32 + quad * 8];
    }

    // incremental hs store base; cells at +0,+64,+128,+192 floats
    float* hsp = &g_hs[dir][((long)(se * 16 + bg) * 128 + (16 * wv + quad)) * 16 + m16];
    const long hsd = (long)step * 32768;

    for (int it = 0; it < S_LEN; it++) {
        const int rd = it & 1, wr = rd ^ 1;

        // (D) prefetch emb fragments for step it+2 (earliest possible issue)
        bf16x8 En[4];
        {
            const int s2 = (it + 2 < S_LEN) ? (it + 2) : (S_LEN - 1);
            const int seP = dir ? (S_LEN - 1 - s2) : s2;
            const int xo2 = xO[seP * 16 + m16];
            #pragma unroll
            for (int kk = 0; kk < 4; kk++)
                En[kk] = *(const bf16x8*)&g_emb[(long)xo2 + kk * 32 + quad * 8];
        }
        // (B) consume: acc = px + W@Hh + W@Hl  (C-chained)
        bf16x8 Hh[4], Hl[4];
        #pragma unroll
        for (int kk = 0; kk < 4; kk++) {
            const int off = ((kk * 4 + quad) * 16 + m16) * 8;
            Hh[kk] = *(const bf16x8*)&hB[rd][0][off];
            Hl[kk] = *(const bf16x8*)&hB[rd][1][off];
        }
        f32x4 acc[4];
        #pragma unroll
        for (int t = 0; t < 4; t++) {
            acc[t] = __builtin_amdgcn_mfma_f32_16x16x32_bf16(W[t][0], Hh[0], px[t], 0, 0, 0);
            #pragma unroll
            for (int kk = 1; kk < 4; kk++)
                acc[t] = __builtin_amdgcn_mfma_f32_16x16x32_bf16(W[t][kk], Hh[kk], acc[t], 0, 0, 0);
            #pragma unroll
            for (int kk = 0; kk < 4; kk++)
                acc[t] = __builtin_amdgcn_mfma_f32_16x16x32_bf16(W[t][kk], Hl[kk], acc[t], 0, 0, 0);
        }
        // (C)+(E) per tile: px' production (MFMA pipe) interleaved with
        // activation + c/h update (VALU/trans pipe)
        #pragma unroll
        for (int t = 0; t < 4; t++) {
            px[t] = __builtin_amdgcn_mfma_f32_16x16x32_bf16(V[t][0], E[0], bias4[t], 0, 0, 0);
            #pragma unroll
            for (int kk = 1; kk < 4; kk++)
                px[t] = __builtin_amdgcn_mfma_f32_16x16x32_bf16(V[t][kk], E[kk], px[t], 0, 0, 0);

            const float iv = fsig(acc[t][0]);
            const float fv = fsig(acc[t][1]);
            const float gv = ftanh(acc[t][2]);
            const float ov = fsig(acc[t][3]);
            c[t] = fv * c[t] + iv * gv;
            const float h = ov * ftanh(c[t]);
            const int u = 16 * wv + 4 * t + quad;
            const unsigned ub = __float_as_uint(h);
            const unsigned hb_ = ub >> 16;
            const float hif = __uint_as_float(ub & 0xFFFF0000u);
            const unsigned lb_ = __float_as_uint(h - hif) >> 16;
            const int ha = (u >> 3) * 128 + m16 * 8 + (u & 7);
            hB[wr][0][ha] = (unsigned short)hb_;
            hB[wr][1][ha] = (unsigned short)lb_;
            hsp[t * 64] = h;                       // +0,+64,+128,+192
        }
        // E <- En (register copy; next step's px uses token it+2)
        #pragma unroll
        for (int kk = 0; kk < 4; kk++) E[kk] = En[kk];

        lds_barrier();   // LDS-only: no vmcnt drain of hs stores / E loads
        hsp += hsd;
    }
}

// -------------------------------------------------------------------------
// Bulk emission from hs layout: block = (s,bg) tile [128u x 16m], staged in
// LDS; thread (m, j<9) dots 256-k. em[r*9+j] includes bout.
// -------------------------------------------------------------------------
__global__ __launch_bounds__(256, 4) void emission_kernel()
{
    __shared__ float hfL[2048], hbL[2048];
    __shared__ float Wsh[T_TAG][256];
    __shared__ float bo[T_TAG];
    const int tid = threadIdx.x, blk = blockIdx.x;   // 0..8191 = s*16+bg
    for (int i = tid; i < T_TAG * 256; i += 256) Wsh[i >> 8][i & 255] = g_wout[i];
    if (tid < T_TAG) bo[tid] = g_bout[tid];
    const float* hf = &g_hs[0][(long)blk * 2048];
    const float* hb = &g_hs[1][(long)blk * 2048];
    for (int i = tid; i < 2048; i += 256) { hfL[i] = hf[i]; hbL[i] = hb[i]; }
    __syncthreads();

    const int m = tid & 15, j = tid >> 4;
    if (j < T_TAG) {
        float acc = bo[j];
        #pragma unroll 4
        for (int u = 0; u < 128; u++)
            acc += hfL[u * 16 + m] * Wsh[j][u] + hbL[u * 16 + m] * Wsh[j][128 + u];
        const int r = (blk >> 4) * 256 + (blk & 15) * 16 + m;   // s*256 + b
        g_em[(long)r * T_TAG + j] = scrub0(acc);
    }
}

// -------------------------------------------------------------------------
// Viterbi: 1 wave per batch element (lanes 0..8 = tags), score broadcast via
// wave shfl — no per-step barrier. Strict-> argmax = jnp first-max.
// Writes EVERY output element (tags all (b,s); scores all b).
// -------------------------------------------------------------------------
__global__ __launch_bounds__(256, 2)
void viterbi_kernel(float* __restrict__ out, int out_size)
{
    __shared__ unsigned char bp[4][S_LEN][T_TAG];
    const int wid  = threadIdx.x >> 6;
    const int lane = threadIdx.x & 63;
    const int b  = blockIdx.x * 4 + wid;
    const int jj = (lane < T_TAG) ? lane : 0;

    float tcol[T_TAG];
    #pragma unroll
    for (int i = 0; i < T_TAG; i++) tcol[i] = g_trans[i * T_TAG + jj];

    float score[T_TAG];
    {
        const float m0 = g_maskf[b * S_LEN + 0];
        #pragma unroll
        for (int i = 0; i < T_TAG; i++)
            score[i] = g_start[i] + g_em[(long)b * T_TAG + i] * m0;
    }
    float e = g_em[((long)1 * B_SZ + b) * T_TAG + jj];
    float m = g_maskf[b * S_LEN + 1];

    for (int s = 1; s < S_LEN; s++) {
        float en = 0.f, mn = 0.f;
        if (s + 1 < S_LEN) {   // prefetch next step
            en = g_em[((long)(s + 1) * B_SZ + b) * T_TAG + jj];
            mn = g_maskf[b * S_LEN + s + 1];
        }
        float best = score[0] + tcol[0];
        int arg = 0;
        #pragma unroll
        for (int i = 1; i < T_TAG; i++) {
            const float cnd = score[i] + tcol[i];
            if (cnd > best) { best = cnd; arg = i; }
        }
        float ns; int nbp;
        if (m > 0.f) { ns = best + e * m; nbp = arg; }
        else         { ns = score[jj];    nbp = jj;  }
        if (lane < T_TAG) bp[wid][s][jj] = (unsigned char)nbp;
        #pragma unroll
        for (int i = 0; i < T_TAG; i++) score[i] = __shfl(ns, i, 64);
        e = en; m = mn;
    }
    #pragma unroll
    for (int i = 0; i < T_TAG; i++) score[i] += g_end[i];

    __syncthreads();   // bp visible for backtrace

    if (lane == 0) {
        float bs = score[0]; int last = 0;
        #pragma unroll
        for (int i = 1; i < T_TAG; i++)
            if (score[i] > bs) { bs = score[i]; last = i; }
        {
            const unsigned u = __float_as_uint(bs);
            if (((u >> 23) & 0xFFu) == 0xFFu) bs = -100.f;
        }
        if ((long)B_SZ * S_LEN + b < out_size)
            out[(long)B_SZ * S_LEN + b] = bs;
        int tag = last;
        if (tag < 0) tag = 0; if (tag > 8) tag = 8;
        out[(long)b * S_LEN + (S_LEN - 1)] = (float)tag;
        for (int s2 = S_LEN - 1; s2 >= 1; s2--) {
            tag = bp[wid][s2][tag];
            if (tag < 0) tag = 0; if (tag > 8) tag = 8;
            out[(long)b * S_LEN + (s2 - 1)] = (float)tag;
        }
    }
}

// -------------------------------------------------------------------------
extern "C" void kernel_launch(void* const* d_in, const int* in_sizes, int n_in,
                              void* d_out, int out_size, void* d_ws, size_t ws_size,
                              hipStream_t stream) {
    const int* x = (const int*)d_in[0];
    float* out = (float*)d_out;

    convert_kernel<<<512, 256, 0, stream>>>(
        d_in[1], d_in[2], d_in[3], d_in[4], d_in[5], d_in[6],
        d_in[7], d_in[8], d_in[9], d_in[10], d_in[11], d_in[12],
        d_in[13], d_in[14], d_in[15]);
    scan_mfma<<<dim3(16, 2), 512, 0, stream>>>(x);
    emission_kernel<<<8192, 256, 0, stream>>>();
    viterbi_kernel<<<64, 256, 0, stream>>>(out, out_size);
}